// Round 10
// baseline (20.785 us; speedup 1.0000x reference)
//
#include <hip/hip_runtime.h>

#define B 4
#define NQ 512
#define NK 512
#define D 128
#define H 32
#define G 4                              // queries per attend block
#define PS 2.8853900817779268f           // 2*log2(e)

typedef float f32x2 __attribute__((ext_vector_type(2)));

__device__ __forceinline__ float rcp_f(float x)  { return __builtin_amdgcn_rcpf(x); }
__device__ __forceinline__ float exp2_f(float x) { return __builtin_amdgcn_exp2f(x); }

// Ek[b][h][k] = exp2(PS*(keys[b,k,:].Wk[:,h] + b1[h]))   (transposed)
// eq[b][q][h] = exp2(PS*(queries[b,q,:].Wq[:,h]))
__global__ __launch_bounds__(256) void proj_kernel(
    const float* __restrict__ keys, const float* __restrict__ queries,
    const float* __restrict__ Wk, const float* __restrict__ Wq,
    const float* __restrict__ b1,
    float* __restrict__ Ek, float* __restrict__ eq)
{
    __shared__ float xs[8][D];
    const int tid = threadIdx.x;
    const int r0 = blockIdx.x * 8;
    const bool is_q = (r0 >= B * NK);
    const float* __restrict__ X = is_q ? (queries + (size_t)(r0 - B * NK) * D)
                                       : (keys + (size_t)r0 * D);
    const float* __restrict__ W = is_q ? Wq : Wk;

    reinterpret_cast<float4*>(&xs[0][0])[tid] =
        reinterpret_cast<const float4*>(X)[tid];
    __syncthreads();

    const int lr = tid >> 5;
    const int h  = tid & 31;
    float a0 = 0.f, a1 = 0.f, a2 = 0.f, a3 = 0.f;
    const float4* x4 = reinterpret_cast<const float4*>(&xs[lr][0]);
    #pragma unroll
    for (int i = 0; i < D / 4; ++i) {
        float4 v = x4[i];
        a0 = fmaf(v.x, W[(4 * i + 0) * H + h], a0);
        a1 = fmaf(v.y, W[(4 * i + 1) * H + h], a1);
        a2 = fmaf(v.z, W[(4 * i + 2) * H + h], a2);
        a3 = fmaf(v.w, W[(4 * i + 3) * H + h], a3);
    }
    float acc = (a0 + a1) + (a2 + a3);
    if (is_q) {
        const int rq = r0 - B * NK + lr;
        eq[(size_t)rq * H + h] = exp2_f(acc * PS);
    } else {
        const int r = r0 + lr;
        const int b = r >> 9;
        const int k = r & (NK - 1);
        Ek[((size_t)b * H + h) * NK + k] = exp2_f((acc + b1[h]) * PS);
    }
}

// One block per (b, G=4 queries). 512 threads. r9 structure; phase 1 uses a
// 4-way rational combine: sum_{h in 4} w_h/d_h = N4/(d0 d1 d2 d3) -> 1 rcp per
// 4 elements (was 4). d_h = 1 + ev_h*ek_h in (1, 2^17.2] => den4 <= 2^69, fp32-safe.
__global__ __launch_bounds__(512) void attend_kernel(
    const float* __restrict__ keys,
    const float* __restrict__ Ek,     // [B][H][NK]
    const float* __restrict__ eq,     // [B][NQ][H]
    const float* __restrict__ w2,
    float* __restrict__ outp)
{
    __shared__ float exw[NK][G];      // 8 KB   normalized weights, [k][g]
    __shared__ float red[8][G];       // wave partial sums
    __shared__ float accm[16][G][D];  // 32 KB  context partials

    const int tid = threadIdx.x;
    const int b   = blockIdx.x >> 7;
    const int q0  = (blockIdx.x & 127) * G;

    // ---- phase 1: logits for key k = tid, queries q0..q0+3
    float acc[G];
    #pragma unroll
    for (int g = 0; g < G; ++g) acc[g] = 0.f;
    const float* Ekc = Ek + (size_t)b * H * NK + tid;      // column base (per-lane)
    const float* eqb = eq + ((size_t)b * NQ + q0) * H;     // uniform base -> s_load

    #pragma unroll
    for (int h4 = 0; h4 < H; h4 += 4) {
        const float ek0 = Ekc[(h4 + 0) * NK];   // coalesced 256B wave loads
        const float ek1 = Ekc[(h4 + 1) * NK];
        const float ek2 = Ekc[(h4 + 2) * NK];
        const float ek3 = Ekc[(h4 + 3) * NK];
        const float w0 = w2[h4 + 0];            // scalar loads
        const float w1 = w2[h4 + 1];
        const float wc = w2[h4 + 2];
        const float w3 = w2[h4 + 3];
        #pragma unroll
        for (int g = 0; g < G; ++g) {
            const float d0 = fmaf(eqb[g * H + h4 + 0], ek0, 1.f);
            const float d1 = fmaf(eqb[g * H + h4 + 1], ek1, 1.f);
            const float d2 = fmaf(eqb[g * H + h4 + 2], ek2, 1.f);
            const float d3 = fmaf(eqb[g * H + h4 + 3], ek3, 1.f);
            const float nab = fmaf(w1, d0, w0 * d1);   // w0/d0 + w1/d1 numerator
            const float ncd = fmaf(w3, d2, wc * d3);
            const float dab = d0 * d1;
            const float dcd = d2 * d3;
            const float n4  = fmaf(nab, dcd, ncd * dab);
            const float d4  = dab * dcd;
            acc[g] = fmaf(n4, rcp_f(d4), acc[g]);      // ONE rcp per 4 h's
        }
    }
    // exponent = -PS * acc  (constant term dropped; softmax shift-invariant;
    // |exponent| <= 2log2e*sum|w2| ~ 16.3 -> no max pass needed, fp32-safe)
    float e0 = exp2_f(-PS * acc[0]);
    float e1 = exp2_f(-PS * acc[1]);
    float e2 = exp2_f(-PS * acc[2]);
    float e3 = exp2_f(-PS * acc[3]);

    // ---- block sum over k: wave shuffle + LDS cross-wave
    float s0 = e0, s1 = e1, s2 = e2, s3 = e3;
    #pragma unroll
    for (int off = 32; off; off >>= 1) {
        s0 += __shfl_xor(s0, off);
        s1 += __shfl_xor(s1, off);
        s2 += __shfl_xor(s2, off);
        s3 += __shfl_xor(s3, off);
    }
    if ((tid & 63) == 0)
        *reinterpret_cast<float4*>(&red[tid >> 6][0]) = float4{s0, s1, s2, s3};
    __syncthreads();
    float4 sum = {0.f, 0.f, 0.f, 0.f};
    #pragma unroll
    for (int p = 0; p < 8; ++p) {
        const float4 v = *reinterpret_cast<const float4*>(&red[p][0]);  // broadcast
        sum.x += v.x; sum.y += v.y; sum.z += v.z; sum.w += v.w;
    }
    *reinterpret_cast<float4*>(&exw[tid][0]) =
        float4{e0 * rcp_f(sum.x), e1 * rcp_f(sum.y),
               e2 * rcp_f(sum.z), e3 * rcp_f(sum.w)};
    __syncthreads();

    // ---- phase 2: context. thread (dg, kp): 32 keys, 4 d's, 4 queries.
    //      f32x2 accumulators invite v_pk_fma_f32 (scalar splat on multiplier).
    const int dg = tid & 31;
    const int kp = tid >> 5;
    const float4* k4 = reinterpret_cast<const float4*>(
        keys + ((size_t)b * NK + kp * 32) * D) + dg;
    f32x2 a0l = {0,0}, a0h = a0l, a1l = a0l, a1h = a0l;
    f32x2 a2l = a0l, a2h = a0l, a3l = a0l, a3h = a0l;
    #pragma unroll 4
    for (int kk = 0; kk < 32; ++kk) {
        const float4 ev = *reinterpret_cast<const float4*>(&exw[kp * 32 + kk][0]); // broadcast
        const float4 kv = k4[(size_t)kk * (D / 4)];
        const f32x2 kl = {kv.x, kv.y};
        const f32x2 kh = {kv.z, kv.w};
        a0l += kl * ev.x;  a0h += kh * ev.x;
        a1l += kl * ev.y;  a1h += kh * ev.y;
        a2l += kl * ev.z;  a2h += kh * ev.z;
        a3l += kl * ev.w;  a3h += kh * ev.w;
    }
    *reinterpret_cast<float4*>(&accm[kp][0][4 * dg]) = float4{a0l.x, a0l.y, a0h.x, a0h.y};
    *reinterpret_cast<float4*>(&accm[kp][1][4 * dg]) = float4{a1l.x, a1l.y, a1h.x, a1h.y};
    *reinterpret_cast<float4*>(&accm[kp][2][4 * dg]) = float4{a2l.x, a2l.y, a2h.x, a2h.y};
    *reinterpret_cast<float4*>(&accm[kp][3][4 * dg]) = float4{a3l.x, a3l.y, a3h.x, a3h.y};
    __syncthreads();

    // ---- reduce 16 partitions; thread t -> output (g,d)
    const int g = tid >> 7;
    const int d = tid & 127;
    float r = 0.f;
    #pragma unroll
    for (int p = 0; p < 16; ++p) r += accm[p][g][d];
    outp[((size_t)b * NQ + q0 + g) * D + d] = r;
}

extern "C" void kernel_launch(void* const* d_in, const int* in_sizes, int n_in,
                              void* d_out, int out_size, void* d_ws, size_t ws_size,
                              hipStream_t stream) {
    const float* keys    = (const float*)d_in[0];
    const float* queries = (const float*)d_in[1];
    const float* Wk      = (const float*)d_in[2];
    const float* Wq      = (const float*)d_in[3];
    const float* b1      = (const float*)d_in[4];
    const float* w2      = (const float*)d_in[5];
    // d_in[6] = b2: dropped (softmax shift-invariant)
    float* out = (float*)d_out;

    float* Ek = (float*)d_ws;                    // B*H*NK floats (transposed)
    float* eq = Ek + (size_t)B * H * NK;         // B*NQ*H floats

    const int proj_blocks = (B * NK + B * NQ) / 8;   // 512
    proj_kernel<<<proj_blocks, 256, 0, stream>>>(keys, queries, Wk, Wq, b1, Ek, eq);
    attend_kernel<<<B * NQ / G, 512, 0, stream>>>(keys, Ek, eq, w2, out);
}